// Round 4
// baseline (246.170 us; speedup 1.0000x reference)
//
#include <hip/hip_runtime.h>
#include <math.h>

#define N_PTS  131072
#define K_DIM  16
#define D_BINS 1024

// Bit-replication of the numpy fp32 reference:
//  - reductions over K accumulate sequentially, ascending k
//  - einsum 'bkn,kd->bnd' = AXPY over outer k: each product and each add
//    rounded separately (numpy einsum SSE loops: mul then add, NO fma)
//  - fp contract(off) so hipcc emits v_mul + v_add, never v_fma
//  - correctly-rounded fp32 div/sqrt (hipcc default, matches SSE)
//  - eps 1e-10 added in fp32 (numpy keeps float32 for py-float scalar)
//  - argmax: strict >, first index wins

__global__ __launch_bounds__(256) void normalize_cmat_np32(
    const float* __restrict__ cmat, float* __restrict__ bnT) {
#pragma clang fp contract(off)
    const int d = blockIdx.x * 256 + threadIdx.x;   // grid = 4 * 256
    if (d >= D_BINS) return;

    float v[K_DIM];
#pragma unroll
    for (int k = 0; k < K_DIM; ++k) v[k] = cmat[k * D_BINS + d];

    float s = v[0];
#pragma unroll
    for (int k = 1; k < K_DIM; ++k) s = s + v[k];        // ascending, sequential
    const float mean = s / 16.0f;                        // exact (pow2)

    float xc[K_DIM], sq[K_DIM];
#pragma unroll
    for (int k = 0; k < K_DIM; ++k) { xc[k] = v[k] - mean; sq[k] = xc[k] * xc[k]; }

    float ss = sq[0];
#pragma unroll
    for (int k = 1; k < K_DIM; ++k) ss = ss + sq[k];     // ascending, sequential
    const float denom = sqrtf(ss) + 1e-10f;

#pragma unroll
    for (int k = 0; k < K_DIM; ++k) bnT[d * K_DIM + k] = xc[k] / denom;
}

__global__ __launch_bounds__(256) void ncc_argmax_np32(
    const float* __restrict__ x, const float* __restrict__ bnT,
    int* __restrict__ out) {
#pragma clang fp contract(off)
    const int n = blockIdx.x * 256 + threadIdx.x;   // grid = 512 * 256

    float v[K_DIM];
#pragma unroll
    for (int k = 0; k < K_DIM; ++k) v[k] = x[(size_t)k * N_PTS + n];

    float s = v[0];
#pragma unroll
    for (int k = 1; k < K_DIM; ++k) s = s + v[k];        // ascending, sequential
    const float mean = s / 16.0f;

    float a[K_DIM], sq[K_DIM];
#pragma unroll
    for (int k = 0; k < K_DIM; ++k) { a[k] = v[k] - mean; sq[k] = a[k] * a[k]; }

    float ss = sq[0];
#pragma unroll
    for (int k = 1; k < K_DIM; ++k) ss = ss + sq[k];     // ascending, sequential
    const float denom = sqrtf(ss) + 1e-10f;
#pragma unroll
    for (int k = 0; k < K_DIM; ++k) a[k] = a[k] / denom;

    float best = -3.402823466e38f;
    int   idx  = 0;

    const float4* b4 = (const float4*)bnT;   // wave-uniform loads
#pragma unroll 2
    for (int d = 0; d < D_BINS; ++d) {
        const float4 b0 = b4[d * 4 + 0];
        const float4 b1 = b4[d * 4 + 1];
        const float4 b2 = b4[d * 4 + 2];
        const float4 b3 = b4[d * 4 + 3];

        // einsum AXPY order: ascending k, each mul and add rounded separately.
        float sc;
        sc = a[0] * b0.x;
        sc = sc + a[1]  * b0.y;
        sc = sc + a[2]  * b0.z;
        sc = sc + a[3]  * b0.w;
        sc = sc + a[4]  * b1.x;
        sc = sc + a[5]  * b1.y;
        sc = sc + a[6]  * b1.z;
        sc = sc + a[7]  * b1.w;
        sc = sc + a[8]  * b2.x;
        sc = sc + a[9]  * b2.y;
        sc = sc + a[10] * b2.z;
        sc = sc + a[11] * b2.w;
        sc = sc + a[12] * b3.x;
        sc = sc + a[13] * b3.y;
        sc = sc + a[14] * b3.z;
        sc = sc + a[15] * b3.w;

        if (sc > best) { best = sc; idx = d; }           // first max wins
    }

    out[n] = idx;
}

extern "C" void kernel_launch(void* const* d_in, const int* in_sizes, int n_in,
                              void* d_out, int out_size, void* d_ws, size_t ws_size,
                              hipStream_t stream) {
    const float* x    = (const float*)d_in[0];   // [1, 16, 131072] fp32
    const float* cmat = (const float*)d_in[1];   // [16, 1024] fp32
    int* out = (int*)d_out;                      // [1, 131072] int32
    float* bnT = (float*)d_ws;                   // 1024*16 floats = 64 KB

    normalize_cmat_np32<<<4, 256, 0, stream>>>(cmat, bnT);
    ncc_argmax_np32<<<512, 256, 0, stream>>>(x, bnT, out);
}